// Round 1
// baseline (987.434 us; speedup 1.0000x reference)
//
#include <hip/hip_runtime.h>

#define DF 128  // feature dim (D_IN == H == 128)

// ---------- small float4 helpers ----------
__device__ __forceinline__ float4 f4_fma(float4 a, float s, float4 acc) {
    acc.x += a.x * s; acc.y += a.y * s; acc.z += a.z * s; acc.w += a.w * s;
    return acc;
}
__device__ __forceinline__ float4 f4_relu(float4 v) {
    v.x = fmaxf(v.x, 0.f); v.y = fmaxf(v.y, 0.f); v.z = fmaxf(v.z, 0.f); v.w = fmaxf(v.w, 0.f);
    return v;
}

// ---------- CSR build ----------
__global__ __launch_bounds__(256) void count_kernel(const int* __restrict__ ei, int E,
                                                    int* __restrict__ counts) {
    int e = blockIdx.x * 256 + threadIdx.x;
    if (e < E) atomicAdd(&counts[ei[E + e]], 1);
}

// single-block scan: exclusive prefix over counts -> row_start, cursor; dis = rsqrt(deg)
__global__ __launch_bounds__(1024) void scan_kernel(const int* __restrict__ counts, int N,
                                                    int* __restrict__ row_start,
                                                    int* __restrict__ cursor,
                                                    float* __restrict__ dis) {
    __shared__ int wtot[16];
    int tid  = threadIdx.x;
    int lane = tid & 63;
    int wid  = tid >> 6;
    int carry = 0;
    for (int base = 0; base < N; base += 1024) {
        int i = base + tid;
        int c = (i < N) ? counts[i] : 0;
        int incl = c;
        #pragma unroll
        for (int off = 1; off < 64; off <<= 1) {
            int n = __shfl_up(incl, off, 64);
            if (lane >= off) incl += n;
        }
        if (lane == 63) wtot[wid] = incl;
        __syncthreads();
        int wbase = 0, total = 0;
        #pragma unroll
        for (int w = 0; w < 16; ++w) {
            int t = wtot[w];
            if (w < wid) wbase += t;
            total += t;
        }
        if (i < N) {
            int excl = carry + wbase + incl - c;
            row_start[i] = excl;
            cursor[i]    = excl;
            dis[i]       = rsqrtf((float)(c + 1));   // +1 self loop
        }
        carry += total;
        __syncthreads();
    }
    if (tid == 0) row_start[N] = carry;
}

__global__ __launch_bounds__(256) void scatter_kernel(const int* __restrict__ ei, int E,
                                                      const float* __restrict__ dis,
                                                      int* __restrict__ cursor,
                                                      int2* __restrict__ edges) {
    int e = blockIdx.x * 256 + threadIdx.x;
    if (e < E) {
        int s = ei[e];
        int d = ei[E + e];
        int pos = atomicAdd(&cursor[d], 1);
        int2 packed;
        packed.x = s;
        packed.y = __float_as_int(dis[s] * dis[d]);
        edges[pos] = packed;
    }
}

// ---------- fp32 GEMM: C[M,128] = (relu_in ? relu(A) : A)[M,128] @ W[128,128] ----------
#define BM 128
#define BK 16
__global__ __launch_bounds__(256) void gemm_kernel(const float* __restrict__ A,
                                                   const float* __restrict__ W,
                                                   float* __restrict__ C,
                                                   int M, int relu_in) {
    __shared__ float As[BK][132];   // transposed A tile, padded (2-way max bank alias)
    __shared__ float Bs[BK][DF];
    int tid = threadIdx.x;
    int tx = tid & 15;   // col group (8 cols each)
    int ty = tid >> 4;   // row group (8 rows each)
    int block_row = blockIdx.x * BM;

    float acc[8][8];
    #pragma unroll
    for (int i = 0; i < 8; ++i)
        #pragma unroll
        for (int j = 0; j < 8; ++j) acc[i][j] = 0.f;

    for (int k0 = 0; k0 < DF; k0 += BK) {
        // A tile: 128 rows x 16 cols, store transposed As[k][m]
        {
            int r  = tid >> 2;   // 0..63
            int cq = tid & 3;    // float4 within the 16 cols
            #pragma unroll
            for (int half = 0; half < 2; ++half) {
                int row = block_row + r + half * 64;
                float4 v = make_float4(0.f, 0.f, 0.f, 0.f);
                if (row < M) v = *(const float4*)&A[(size_t)row * DF + k0 + cq * 4];
                if (relu_in) v = f4_relu(v);
                int m = r + half * 64;
                As[cq * 4 + 0][m] = v.x;
                As[cq * 4 + 1][m] = v.y;
                As[cq * 4 + 2][m] = v.z;
                As[cq * 4 + 3][m] = v.w;
            }
        }
        // B tile: 16 rows x 128 cols
        {
            int kr = tid >> 5;   // 0..7
            int f4 = tid & 31;
            #pragma unroll
            for (int half = 0; half < 2; ++half) {
                int k = kr + half * 8;
                float4 v = *(const float4*)&W[(size_t)(k0 + k) * DF + f4 * 4];
                *(float4*)&Bs[k][f4 * 4] = v;
            }
        }
        __syncthreads();
        #pragma unroll
        for (int kk = 0; kk < BK; ++kk) {
            float a[8], b[8];
            *(float4*)&a[0] = *(const float4*)&As[kk][ty * 8];
            *(float4*)&a[4] = *(const float4*)&As[kk][ty * 8 + 4];
            *(float4*)&b[0] = *(const float4*)&Bs[kk][tx * 8];
            *(float4*)&b[4] = *(const float4*)&Bs[kk][tx * 8 + 4];
            #pragma unroll
            for (int i = 0; i < 8; ++i)
                #pragma unroll
                for (int j = 0; j < 8; ++j)
                    acc[i][j] += a[i] * b[j];
        }
        __syncthreads();
    }

    #pragma unroll
    for (int i = 0; i < 8; ++i) {
        int row = block_row + ty * 8 + i;
        if (row < M) {
            float4 v0 = make_float4(acc[i][0], acc[i][1], acc[i][2], acc[i][3]);
            float4 v1 = make_float4(acc[i][4], acc[i][5], acc[i][6], acc[i][7]);
            *(float4*)&C[(size_t)row * DF + tx * 8]     = v0;
            *(float4*)&C[(size_t)row * DF + tx * 8 + 4] = v1;
        }
    }
}

// ---------- aggregation: out[i] = sum_{e into i} h[src]*norm + h[i]*dis[i]^2 + b ----------
__global__ __launch_bounds__(256) void agg_kernel(const float* __restrict__ h,
                                                  const int2* __restrict__ edges,
                                                  const int* __restrict__ row_start,
                                                  const float* __restrict__ dis,
                                                  const float* __restrict__ bias,
                                                  float* __restrict__ out, int N) {
    int gid = blockIdx.x * 8 + (threadIdx.x >> 5);   // node
    int l4  = threadIdx.x & 31;                      // float4 slot (32 x 4 = 128 feats)
    if (gid >= N) return;
    const float4* h4 = (const float4*)h;
    float d  = dis[gid];
    float sn = d * d;                                // self-loop norm
    float4 acc = h4[(size_t)gid * 32 + l4];
    float4 bv  = ((const float4*)bias)[l4];
    acc.x = acc.x * sn + bv.x;
    acc.y = acc.y * sn + bv.y;
    acc.z = acc.z * sn + bv.z;
    acc.w = acc.w * sn + bv.w;
    int s = row_start[gid], e = row_start[gid + 1];
    for (int p = s; p < e; ++p) {
        int2 ed = edges[p];
        float w = __int_as_float(ed.y);
        float4 v = h4[(size_t)ed.x * 32 + l4];
        acc = f4_fma(v, w, acc);
    }
    ((float4*)out)[(size_t)gid * 32 + l4] = acc;
}

// ---------- final: out[i] = relu(h[i]) . Wf + bf ----------
__global__ __launch_bounds__(256) void final_kernel(const float* __restrict__ h,
                                                    const float* __restrict__ Wf,
                                                    const float* __restrict__ bf,
                                                    float* __restrict__ out, int N) {
    int gid = blockIdx.x * 8 + (threadIdx.x >> 5);
    int l4  = threadIdx.x & 31;
    if (gid >= N) return;
    float4 v = f4_relu(((const float4*)h)[(size_t)gid * 32 + l4]);
    float4 w = ((const float4*)Wf)[l4];
    float p = v.x * w.x + v.y * w.y + v.z * w.z + v.w * w.w;
    #pragma unroll
    for (int off = 16; off > 0; off >>= 1) p += __shfl_xor(p, off, 64);
    if (l4 == 0) out[gid] = p + bf[0];
}

extern "C" void kernel_launch(void* const* d_in, const int* in_sizes, int n_in,
                              void* d_out, int out_size, void* d_ws, size_t ws_size,
                              hipStream_t stream) {
    const float* x  = (const float*)d_in[0];
    const int*   ei = (const int*)d_in[1];
    const float* Ws = (const float*)d_in[2];
    const float* bs = (const float*)d_in[3];
    const float* Wf = (const float*)d_in[4];
    const float* bf = (const float*)d_in[5];
    float* out = (float*)d_out;

    int N = in_sizes[0] / DF;
    int E = in_sizes[1] / 2;
    int L = in_sizes[2] / (DF * DF);

    // workspace carve-out (aligned to 256B)
    char* p = (char*)d_ws;
    auto alloc = [&](size_t bytes) {
        char* r = p;
        p += (bytes + 255) & ~(size_t)255;
        return r;
    };
    int*   counts    = (int*)alloc((size_t)N * 4);
    int*   row_start = (int*)alloc((size_t)(N + 1) * 4);
    int*   cursor    = (int*)alloc((size_t)N * 4);
    float* dis       = (float*)alloc((size_t)N * 4);
    int2*  edges     = (int2*)alloc((size_t)E * 8);
    float* bufA      = (float*)alloc((size_t)N * DF * 4);
    float* bufB      = (float*)alloc((size_t)N * DF * 4);

    hipMemsetAsync(counts, 0, (size_t)N * 4, stream);
    count_kernel<<<(E + 255) / 256, 256, 0, stream>>>(ei, E, counts);
    scan_kernel<<<1, 1024, 0, stream>>>(counts, N, row_start, cursor, dis);
    scatter_kernel<<<(E + 255) / 256, 256, 0, stream>>>(ei, E, dis, cursor, edges);

    const float* hin = x;
    for (int l = 0; l < L; ++l) {
        gemm_kernel<<<(N + BM - 1) / BM, 256, 0, stream>>>(hin, Ws + (size_t)l * DF * DF,
                                                           bufA, N, l > 0);
        agg_kernel<<<(N + 7) / 8, 256, 0, stream>>>(bufA, edges, row_start, dis,
                                                    bs + (size_t)l * DF, bufB, N);
        hin = bufB;
    }
    final_kernel<<<(N + 7) / 8, 256, 0, stream>>>(bufB, Wf, bf, out, N);
}

// Round 2
// 747.291 us; speedup vs baseline: 1.3214x; 1.3214x over previous
//
#include <hip/hip_runtime.h>

#define DF 128  // feature dim (D_IN == H == 128)

typedef short bf16x8 __attribute__((ext_vector_type(8)));
typedef float f32x4 __attribute__((ext_vector_type(4)));

// ---------- helpers ----------
__device__ __forceinline__ float4 f4_fma(float4 a, float s, float4 acc) {
    acc.x += a.x * s; acc.y += a.y * s; acc.z += a.z * s; acc.w += a.w * s;
    return acc;
}
__device__ __forceinline__ float4 f4_relu(float4 v) {
    v.x = fmaxf(v.x, 0.f); v.y = fmaxf(v.y, 0.f); v.z = fmaxf(v.z, 0.f); v.w = fmaxf(v.w, 0.f);
    return v;
}
__device__ __forceinline__ unsigned short f32_to_bf16_rne(float f) {
    unsigned u = __float_as_uint(f);
    unsigned r = (u + 0x7fffu + ((u >> 16) & 1u)) >> 16;
    return (unsigned short)r;
}
__device__ __forceinline__ float bf16_to_f32(unsigned short h) {
    return __uint_as_float(((unsigned)h) << 16);
}
// split 8 floats into hi/lo bf16 fragments
__device__ __forceinline__ void split8(float4 a, float4 b, bf16x8& hi, bf16x8& lo) {
    float v[8] = {a.x, a.y, a.z, a.w, b.x, b.y, b.z, b.w};
    #pragma unroll
    for (int j = 0; j < 8; ++j) {
        unsigned short h = f32_to_bf16_rne(v[j]);
        hi[j] = (short)h;
        float rem = v[j] - bf16_to_f32(h);
        lo[j] = (short)f32_to_bf16_rne(rem);
    }
}

// ---------- CSR build ----------
__global__ __launch_bounds__(256) void count_kernel(const int* __restrict__ ei, int E,
                                                    int* __restrict__ counts) {
    int e = blockIdx.x * 256 + threadIdx.x;
    if (e < E) atomicAdd(&counts[ei[E + e]], 1);
}

// Phase A: per-block sums of counts (1024 elems per block)
__global__ __launch_bounds__(1024) void scan_partials_kernel(const int* __restrict__ counts, int N,
                                                             int* __restrict__ partials) {
    __shared__ int wsum[16];
    int t = threadIdx.x, lane = t & 63, wid = t >> 6;
    int i = blockIdx.x * 1024 + t;
    int c = (i < N) ? counts[i] : 0;
    #pragma unroll
    for (int off = 32; off > 0; off >>= 1) c += __shfl_xor(c, off, 64);
    if (lane == 0) wsum[wid] = c;
    __syncthreads();
    if (t == 0) {
        int s = 0;
        #pragma unroll
        for (int w = 0; w < 16; ++w) s += wsum[w];
        partials[blockIdx.x] = s;
    }
}

// Phase B: single-block exclusive scan over NB (<=1024) partials; writes total to row_end
__global__ __launch_bounds__(1024) void scan_offsets_kernel(int* __restrict__ partials, int NB,
                                                            int* __restrict__ row_end) {
    __shared__ int wtot[16];
    int t = threadIdx.x, lane = t & 63, wid = t >> 6;
    int c = (t < NB) ? partials[t] : 0;
    int incl = c;
    #pragma unroll
    for (int off = 1; off < 64; off <<= 1) {
        int n = __shfl_up(incl, off, 64);
        if (lane >= off) incl += n;
    }
    if (lane == 63) wtot[wid] = incl;
    __syncthreads();
    int wbase = 0, total = 0;
    #pragma unroll
    for (int w = 0; w < 16; ++w) {
        int v = wtot[w];
        if (w < wid) wbase += v;
        total += v;
    }
    if (t < NB) partials[t] = wbase + incl - c;
    if (t == 0) *row_end = total;
}

// Phase C: local scan + block offset -> row_start/cursor/dis
__global__ __launch_bounds__(1024) void scan_write_kernel(const int* __restrict__ counts, int N,
                                                          const int* __restrict__ partials,
                                                          int* __restrict__ row_start,
                                                          int* __restrict__ cursor,
                                                          float* __restrict__ dis) {
    __shared__ int wtot[16];
    int t = threadIdx.x, lane = t & 63, wid = t >> 6;
    int i = blockIdx.x * 1024 + t;
    int c = (i < N) ? counts[i] : 0;
    int incl = c;
    #pragma unroll
    for (int off = 1; off < 64; off <<= 1) {
        int n = __shfl_up(incl, off, 64);
        if (lane >= off) incl += n;
    }
    if (lane == 63) wtot[wid] = incl;
    __syncthreads();
    int wbase = 0;
    #pragma unroll
    for (int w = 0; w < 16; ++w) {
        int v = wtot[w];
        if (w < wid) wbase += v;
    }
    if (i < N) {
        int excl = partials[blockIdx.x] + wbase + incl - c;
        row_start[i] = excl;
        cursor[i]    = excl;
        dis[i]       = rsqrtf((float)(c + 1));   // +1 self loop
    }
}

__global__ __launch_bounds__(256) void scatter_kernel(const int* __restrict__ ei, int E,
                                                      const float* __restrict__ dis,
                                                      int* __restrict__ cursor,
                                                      int2* __restrict__ edges) {
    int e = blockIdx.x * 256 + threadIdx.x;
    if (e < E) {
        int s = ei[e];
        int d = ei[E + e];
        int pos = atomicAdd(&cursor[d], 1);
        int2 packed;
        packed.x = s;
        packed.y = __float_as_int(dis[s] * dis[d]);
        edges[pos] = packed;
    }
}

// ---------- MFMA split-bf16 GEMM: C[M,128] = (relu?relu(A):A) @ W ----------
// Block: 256 threads = 4 waves; each wave computes 32 rows x 128 cols.
// W fragments (hi/lo bf16) staged once per block into LDS in fragment order:
//   tuple g=(s*8+n)*64+l holds 8 bf16: frag elem j <-> W[s*32+4*(l>>4)+(j&3)+16*(j>>2)][n*16+(l&15)]
#define GBM 128
__global__ __launch_bounds__(256, 2) void gemm_mfma(const float* __restrict__ A,
                                                    const float* __restrict__ W,
                                                    float* __restrict__ C,
                                                    int M, int relu) {
    __shared__ unsigned short WH[16384];  // 32 KB
    __shared__ unsigned short WL[16384];  // 32 KB
    int tid = threadIdx.x;

    // stage W fragments (hi/lo)
    #pragma unroll
    for (int i = 0; i < 8; ++i) {
        int g = tid + i * 256;            // 2048 tuples
        int s = g >> 9;
        int n = (g >> 6) & 7;
        int l = g & 63;
        int kb = s * 32 + ((l >> 4) << 2);
        int c  = n * 16 + (l & 15);
        bf16x8 hi, lo;
        #pragma unroll
        for (int j = 0; j < 8; ++j) {
            int k = kb + (j & 3) + ((j >> 2) << 4);
            float w = W[k * DF + c];
            unsigned short h = f32_to_bf16_rne(w);
            hi[j] = (short)h;
            lo[j] = (short)f32_to_bf16_rne(w - bf16_to_f32(h));
        }
        *(bf16x8*)&WH[g * 8] = hi;
        *(bf16x8*)&WL[g * 8] = lo;
    }
    __syncthreads();

    int wid  = tid >> 6;
    int lane = tid & 63;
    int l15  = lane & 15;
    int l4   = lane >> 4;
    size_t row0 = (size_t)blockIdx.x * GBM + wid * 32;

    f32x4 acc[2][8];
    #pragma unroll
    for (int tr = 0; tr < 2; ++tr)
        #pragma unroll
        for (int n = 0; n < 8; ++n) acc[tr][n] = (f32x4)(0.f);

    const float* Ar0 = A + (row0 + l15) * DF;
    const float* Ar1 = A + (row0 + 16 + l15) * DF;
    bool ok0 = (row0 + l15) < (size_t)M;
    bool ok1 = (row0 + 16 + l15) < (size_t)M;
    float4 zero = make_float4(0.f, 0.f, 0.f, 0.f);

    #pragma unroll
    for (int s = 0; s < 4; ++s) {
        int c0 = s * 32 + l4 * 4;
        float4 a00 = ok0 ? *(const float4*)&Ar0[c0]      : zero;
        float4 a01 = ok0 ? *(const float4*)&Ar0[c0 + 16] : zero;
        float4 a10 = ok1 ? *(const float4*)&Ar1[c0]      : zero;
        float4 a11 = ok1 ? *(const float4*)&Ar1[c0 + 16] : zero;
        if (relu) {
            a00 = f4_relu(a00); a01 = f4_relu(a01);
            a10 = f4_relu(a10); a11 = f4_relu(a11);
        }
        bf16x8 ah0, al0, ah1, al1;
        split8(a00, a01, ah0, al0);
        split8(a10, a11, ah1, al1);
        #pragma unroll
        for (int n = 0; n < 8; ++n) {
            int g = ((s * 8 + n) * 64 + lane) * 8;
            bf16x8 bh = *(const bf16x8*)&WH[g];
            bf16x8 bl = *(const bf16x8*)&WL[g];
            acc[0][n] = __builtin_amdgcn_mfma_f32_16x16x32_bf16(ah0, bh, acc[0][n], 0, 0, 0);
            acc[0][n] = __builtin_amdgcn_mfma_f32_16x16x32_bf16(ah0, bl, acc[0][n], 0, 0, 0);
            acc[0][n] = __builtin_amdgcn_mfma_f32_16x16x32_bf16(al0, bh, acc[0][n], 0, 0, 0);
            acc[1][n] = __builtin_amdgcn_mfma_f32_16x16x32_bf16(ah1, bh, acc[1][n], 0, 0, 0);
            acc[1][n] = __builtin_amdgcn_mfma_f32_16x16x32_bf16(ah1, bl, acc[1][n], 0, 0, 0);
            acc[1][n] = __builtin_amdgcn_mfma_f32_16x16x32_bf16(al1, bh, acc[1][n], 0, 0, 0);
        }
    }

    // C/D layout: col = n*16 + (lane&15), row = tr*16 + (lane>>4)*4 + q
    #pragma unroll
    for (int tr = 0; tr < 2; ++tr) {
        size_t rbase = row0 + tr * 16 + l4 * 4;
        #pragma unroll
        for (int q = 0; q < 4; ++q) {
            size_t r = rbase + q;
            if (r < (size_t)M) {
                #pragma unroll
                for (int n = 0; n < 8; ++n)
                    C[r * DF + n * 16 + l15] = acc[tr][n][q];
            }
        }
    }
}

// ---------- aggregation: out[i] = sum_{e into i} h[src]*norm + h[i]*dis[i]^2 + b ----------
// FINAL=1: fuse relu + (.)@Wf + bf, write scalar per node to out.
template <int FINAL>
__global__ __launch_bounds__(256) void agg_kernel(const float* __restrict__ h,
                                                  const int2* __restrict__ edges,
                                                  const int* __restrict__ row_start,
                                                  const float* __restrict__ dis,
                                                  const float* __restrict__ bias,
                                                  const float* __restrict__ Wf,
                                                  const float* __restrict__ bf,
                                                  float* __restrict__ out, int N) {
    int gid = blockIdx.x * 8 + (threadIdx.x >> 5);   // node
    int l4  = threadIdx.x & 31;                      // float4 slot (32 x 4 = 128 feats)
    if (gid >= N) return;
    const float4* h4 = (const float4*)h;
    float d  = dis[gid];
    float sn = d * d;                                // self-loop norm
    float4 acc = h4[(size_t)gid * 32 + l4];
    float4 bv  = ((const float4*)bias)[l4];
    acc.x = acc.x * sn + bv.x;
    acc.y = acc.y * sn + bv.y;
    acc.z = acc.z * sn + bv.z;
    acc.w = acc.w * sn + bv.w;
    int s = row_start[gid], e = row_start[gid + 1];
    for (int p = s; p < e; ++p) {
        int2 ed = edges[p];
        float w = __int_as_float(ed.y);
        float4 v = h4[(size_t)ed.x * 32 + l4];
        acc = f4_fma(v, w, acc);
    }
    if (FINAL) {
        acc = f4_relu(acc);
        float4 w = ((const float4*)Wf)[l4];
        float p = acc.x * w.x + acc.y * w.y + acc.z * w.z + acc.w * w.w;
        #pragma unroll
        for (int off = 16; off > 0; off >>= 1) p += __shfl_xor(p, off, 32);
        if (l4 == 0) out[gid] = p + bf[0];
    } else {
        ((float4*)out)[(size_t)gid * 32 + l4] = acc;
    }
}

extern "C" void kernel_launch(void* const* d_in, const int* in_sizes, int n_in,
                              void* d_out, int out_size, void* d_ws, size_t ws_size,
                              hipStream_t stream) {
    const float* x  = (const float*)d_in[0];
    const int*   ei = (const int*)d_in[1];
    const float* Ws = (const float*)d_in[2];
    const float* bs = (const float*)d_in[3];
    const float* Wf = (const float*)d_in[4];
    const float* bf = (const float*)d_in[5];
    float* out = (float*)d_out;

    int N = in_sizes[0] / DF;
    int E = in_sizes[1] / 2;
    int L = in_sizes[2] / (DF * DF);

    char* p = (char*)d_ws;
    auto alloc = [&](size_t bytes) {
        char* r = p;
        p += (bytes + 255) & ~(size_t)255;
        return r;
    };
    int*   counts    = (int*)alloc((size_t)N * 4);
    int*   row_start = (int*)alloc((size_t)(N + 1) * 4);
    int*   cursor    = (int*)alloc((size_t)N * 4);
    float* dis       = (float*)alloc((size_t)N * 4);
    int2*  edges     = (int2*)alloc((size_t)E * 8);
    float* bufA      = (float*)alloc((size_t)N * DF * 4);
    float* bufB      = (float*)alloc((size_t)N * DF * 4);
    int*   partials  = (int*)alloc(1024 * 4);

    int NB = (N + 1023) / 1024;

    hipMemsetAsync(counts, 0, (size_t)N * 4, stream);
    count_kernel<<<(E + 255) / 256, 256, 0, stream>>>(ei, E, counts);
    scan_partials_kernel<<<NB, 1024, 0, stream>>>(counts, N, partials);
    scan_offsets_kernel<<<1, 1024, 0, stream>>>(partials, NB, &row_start[N]);
    scan_write_kernel<<<NB, 1024, 0, stream>>>(counts, N, partials, row_start, cursor, dis);
    scatter_kernel<<<(E + 255) / 256, 256, 0, stream>>>(ei, E, dis, cursor, edges);

    const float* hin = x;
    for (int l = 0; l < L; ++l) {
        gemm_mfma<<<(N + GBM - 1) / GBM, 256, 0, stream>>>(hin, Ws + (size_t)l * DF * DF,
                                                           bufA, N, l > 0);
        if (l == L - 1) {
            agg_kernel<1><<<(N + 7) / 8, 256, 0, stream>>>(bufA, edges, row_start, dis,
                                                           bs + (size_t)l * DF, Wf, bf, out, N);
        } else {
            agg_kernel<0><<<(N + 7) / 8, 256, 0, stream>>>(bufA, edges, row_start, dis,
                                                           bs + (size_t)l * DF, nullptr, nullptr,
                                                           bufB, N);
            hin = bufB;
        }
    }
}